// Round 15
// baseline (951.652 us; speedup 1.0000x reference)
//
#include <hip/hip_runtime.h>

typedef __attribute__((ext_vector_type(4))) float f32x4;
typedef __attribute__((ext_vector_type(8))) short s16x8;
typedef __attribute__((ext_vector_type(4))) unsigned int u32x4;
typedef unsigned short USHORT;

static __device__ __forceinline__ USHORT f2bf(float f){
  unsigned u = __float_as_uint(f);
  u += 0x7FFFu + ((u>>16)&1u);
  return (USHORT)(u>>16);
}
static __device__ __forceinline__ float bflo(unsigned u){ return __uint_as_float(u<<16); }
static __device__ __forceinline__ float bfhi(unsigned u){ return __uint_as_float(u & 0xFFFF0000u); }

static __device__ __forceinline__ void glds16(const void* g, void* l){
  typedef __attribute__((address_space(1))) const unsigned int guint;
  typedef __attribute__((address_space(3))) unsigned int luint;
  __builtin_amdgcn_global_load_lds((guint*)g, (luint*)l, 16, 0, 0);
}
static __device__ __forceinline__ void glds4(const void* g, void* l){
  typedef __attribute__((address_space(1))) const unsigned int guint;
  typedef __attribute__((address_space(3))) unsigned int luint;
  __builtin_amdgcn_global_load_lds((guint*)g, (luint*)l, 4, 0, 0);
}

// ---------------- fp32 -> bf16 convert ----------------
__global__ void k_convert(const float* __restrict__ src, USHORT* __restrict__ dst, int n4){
  for (int i = blockIdx.x*blockDim.x + threadIdx.x; i < n4; i += gridDim.x*blockDim.x){
    float4 v = ((const float4*)src)[i];
    ushort4 o; o.x=f2bf(v.x); o.y=f2bf(v.y); o.z=f2bf(v.z); o.w=f2bf(v.w);
    ((ushort4*)dst)[i] = o;
  }
}

// ---------------- transpose+convert: src fp32 [K][N] -> dst bf16 [N][K] ----------------
__global__ __launch_bounds__(256) void k_transpose(const float* __restrict__ src,
    USHORT* __restrict__ dst, int K, int N)
{
  __shared__ float tile[64][65];
  int tx = threadIdx.x & 15, ty = threadIdx.x >> 4;
  size_t k0 = (size_t)blockIdx.x*64, n0 = (size_t)blockIdx.y*64;
  #pragma unroll
  for (int j=0;j<4;j++){
    int row = j*16 + ty;
    float4 v = *(const float4*)&src[(k0+row)*(size_t)N + n0 + tx*4];
    tile[row][tx*4+0] = v.x; tile[row][tx*4+1] = v.y;
    tile[row][tx*4+2] = v.z; tile[row][tx*4+3] = v.w;
  }
  __syncthreads();
  #pragma unroll
  for (int j=0;j<4;j++){
    int nn = j*16 + ty;
    ushort4 o;
    o.x = f2bf(tile[tx*4+0][nn]);
    o.y = f2bf(tile[tx*4+1][nn]);
    o.z = f2bf(tile[tx*4+2][nn]);
    o.w = f2bf(tile[tx*4+3][nn]);
    *(ushort4*)&dst[(n0+nn)*(size_t)K + k0 + tx*4] = o;
  }
}

// ---------------- 256x256 BK=32 8-wave GEMM, 3-buffer counted-vmcnt pipeline ----------
// k_gemmdb's proven pattern at 256^2: per tile {wait vmcnt(4); s_barrier; reads+32 MFMA;
// s_barrier; stage kt+2 into buf (kt+2)%3}. No vmcnt(0) in the main loop; each tile's
// loads have ~2 tiles of slack. LDS 96 KB (3 x (A16K+B16K)); swizzle blk^((row>>1)&3).
__global__ __launch_bounds__(512, 1) void k_gemm256(const USHORT* __restrict__ A,
    const USHORT* __restrict__ B, const float* __restrict__ bias,
    USHORT* __restrict__ outA, int K)
{
  __shared__ __align__(16) char smem[98304];
  const int tid = threadIdx.x, lane = tid&63, wave = tid>>6;
  const int wr = wave>>2, wc = wave&3, l15 = lane&15, l4 = lane>>4;

  const int gx = gridDim.x;
  int flatb = blockIdx.y*gx + blockIdx.x;
  int nwg  = gx*gridDim.y;
  int swz  = (flatb & 7)*(nwg>>3) + (flatb>>3);
  const size_t m0 = (size_t)(swz % gx)*256, n0 = (size_t)(swz / gx)*256;

  f32x4 acc[8][4];
  #pragma unroll
  for (int r=0;r<8;r++){
    #pragma unroll
    for (int c=0;c<4;c++) acc[r][c] = f32x4{0.f,0.f,0.f,0.f};
  }
  const int nk = K>>5;   // 32 K-tiles of 32

  const char* Abase = (const char*)A + ((m0*(size_t)K)<<1);
  const char* Bbase = (const char*)B + ((n0*(size_t)K)<<1);
  unsigned sro[2];
  #pragma unroll
  for (int q=0;q<2;q++){
    const int idx = q*512 + tid;
    const int row = idx>>2, blk = idx&3;
    sro[q] = ((unsigned)(row*K)<<1) + (unsigned)((blk ^ ((row>>1)&3))<<4);
  }

  // hoisted LDS element offsets (loop-invariant); rows are 32 elements (64 B)
  unsigned aOff[8], bOff[4];
  #pragma unroll
  for (int r=0;r<8;r++){
    const int rowa = wr*128 + r*16 + l15;
    aOff[r] = rowa*32 + ((l4 ^ ((rowa>>1)&3))<<3);
  }
  #pragma unroll
  for (int n=0;n<4;n++){
    const int rowb = wc*64 + n*16 + l15;
    bOff[n] = rowb*32 + ((l4 ^ ((rowb>>1)&3))<<3);
  }

  #define SG_A(buf, kt, q) glds16(Abase + sro[q] + ((unsigned)(kt)<<6), \
                                  smem + (buf)*32768 + ((q)*512+tid)*16)
  #define SG_B(buf, kt, q) glds16(Bbase + sro[q] + ((unsigned)(kt)<<6), \
                                  smem + (buf)*32768 + 16384 + ((q)*512+tid)*16)

  SG_A(0,0,0); SG_A(0,0,1); SG_B(0,0,0); SG_B(0,0,1);
  SG_A(1,1,0); SG_A(1,1,1); SG_B(1,1,0); SG_B(1,1,1);

  int cur = 0;
  for (int kt=0; kt<nk; ++kt){
    if (kt+1 < nk) asm volatile("s_waitcnt vmcnt(4)" ::: "memory");
    else           asm volatile("s_waitcnt vmcnt(0)" ::: "memory");
    __builtin_amdgcn_s_barrier();
    const USHORT* Ab = (const USHORT*)(smem + cur*32768);
    const USHORT* Bb = (const USHORT*)(smem + cur*32768 + 16384);
    s16x8 af[8], bf[4];
    #pragma unroll
    for (int r=0;r<8;r++) af[r] = *(const s16x8*)&Ab[aOff[r]];
    #pragma unroll
    for (int n=0;n<4;n++) bf[n] = *(const s16x8*)&Bb[bOff[n]];
    #pragma unroll
    for (int r=0;r<8;r++){
      #pragma unroll
      for (int n=0;n<4;n++)
        acc[r][n] = __builtin_amdgcn_mfma_f32_16x16x32_bf16(af[r], bf[n], acc[r][n], 0,0,0);
    }
    __builtin_amdgcn_s_barrier();
    if (kt+2 < nk){
      const int nb = (cur+2 >= 3) ? cur-1 : cur+2;
      SG_A(nb, kt+2, 0); SG_A(nb, kt+2, 1); SG_B(nb, kt+2, 0); SG_B(nb, kt+2, 1);
    }
    cur = (cur+1 == 3) ? 0 : cur+1;
  }
  #undef SG_A
  #undef SG_B

  // epilogue: two passes, Ct [256][128] bf16 (64 KB), r5-verified swizzle + nt stores
  __syncthreads();
  USHORT* Ct = (USHORT*)smem;
  #pragma unroll
  for (int p=0;p<2;p++){
    if ((wc>>1) == p){
      #pragma unroll
      for (int n=0;n<4;n++){
        const int col = (wc&1)*64 + n*16 + l15;      // 0..127 within pass
        const size_t gc = n0 + p*128 + col;
        const bool diag = ((int)(gc>>7) == (int)(gc&127));
        const float bv = bias[gc];
        #pragma unroll
        for (int mf=0;mf<8;mf++){
          #pragma unroll
          for (int q=0;q<4;q++){
            const int row = wr*128 + mf*16 + l4*4 + q;  // 0..255
            float v = acc[mf][n][q] + bv;
            float e = exp2f(v * 2.885390081777927f);
            float tnh = 1.0f - 2.0f/(e + 1.0f);
            tnh = diag ? 0.0f : tnh*0.08838834764831845f;
            Ct[row*128 + (col ^ (((row>>2)&3)<<4))] = f2bf(tnh);
          }
        }
      }
    }
    __syncthreads();
    #pragma unroll
    for (int it=0; it<8; ++it){
      const int flat = it*512 + tid;
      const int row = flat>>4, b16 = flat&15;
      const int phys = b16 ^ (((row>>2)&3)<<1);
      u32x4 v = *(const u32x4*)&Ct[row*128 + phys*8];
      __builtin_nontemporal_store(v, (u32x4*)(outA + (m0+row)*16384 + n0 + p*128 + b16*8));
    }
    __syncthreads();
  }
}

// ---------------- small GEMM (d & B projections) ----------
__global__ __launch_bounds__(256) void k_gemmdb(const USHORT* __restrict__ A,
    const USHORT* __restrict__ B, const float* __restrict__ bias,
    const float* __restrict__ bias2,
    float* __restrict__ outd, float* __restrict__ outB, int K)
{
  __shared__ __align__(16) char smem[32768];
  const int tid = threadIdx.x, lane = tid&63, wave = tid>>6;
  const int wr = wave>>1, wc = wave&1, l15 = lane&15, l4 = lane>>4;
  const size_t m0 = (size_t)blockIdx.x*128, n0 = (size_t)blockIdx.y*128;

  f32x4 acc[4][4];
  #pragma unroll
  for (int r=0;r<4;r++){
    #pragma unroll
    for (int c=0;c<4;c++) acc[r][c] = f32x4{0.f,0.f,0.f,0.f};
  }
  const int nk = K>>5;
  const int srow = tid>>2; const int skb = (tid&3)*16;

  #define GSTAGE(buf, kt) do { \
    _Pragma("unroll") \
    for (int j=0;j<2;j++){ \
      glds16((const char*)A + ((m0 + j*64 + srow)*(size_t)K + (size_t)(kt)*32)*2 + skb, \
             smem + (buf)*8192 + j*4096 + wave*1024); \
      glds16((const char*)B + ((n0 + j*64 + srow)*(size_t)K + (size_t)(kt)*32)*2 + skb, \
             smem + 16384 + (buf)*8192 + j*4096 + wave*1024); \
    } \
  } while(0)

  GSTAGE(0, 0);
  GSTAGE(1, 1);
  for (int kt=0; kt<nk; ++kt){
    const int cur = kt&1;
    if (kt+1 < nk) asm volatile("s_waitcnt vmcnt(4)" ::: "memory");
    else           asm volatile("s_waitcnt vmcnt(0)" ::: "memory");
    __builtin_amdgcn_s_barrier();
    const USHORT* At = (const USHORT*)(smem + cur*8192);
    const USHORT* Bt = (const USHORT*)(smem + 16384 + cur*8192);
    s16x8 af[4], bf[4];
    #pragma unroll
    for (int r=0;r<4;r++) af[r] = *(const s16x8*)&At[(wr*64 + r*16 + l15)*32 + l4*8];
    #pragma unroll
    for (int c=0;c<4;c++) bf[c] = *(const s16x8*)&Bt[(wc*64 + c*16 + l15)*32 + l4*8];
    #pragma unroll
    for (int r=0;r<4;r++){
      #pragma unroll
      for (int c=0;c<4;c++)
        acc[r][c] = __builtin_amdgcn_mfma_f32_16x16x32_bf16(af[r], bf[c], acc[r][c], 0,0,0);
    }
    __builtin_amdgcn_s_barrier();
    if (kt+2 < nk) GSTAGE(cur, kt+2);
  }
  #undef GSTAGE

  #pragma unroll
  for (int r=0;r<4;r++){
    const int rowb = wr*64 + r*16 + l4*4;
    #pragma unroll
    for (int c=0;c<4;c++){
      const size_t gc = n0 + wc*64 + c*16 + l15;
      #pragma unroll
      for (int q=0;q<4;q++){
        const size_t grow = m0 + rowb + q;
        float v = acc[r][c][q];
        if ((int)gc < 128){
          float sgm = v + bias[gc];
          float e = exp2f(-sgm * 1.4426950408889634f);
          outd[grow*128 + gc] = 1.0f/(1.0f + e);
        } else {
          outB[grow*128 + (gc-128)] = v + bias2[gc-128];
        }
      }
    }
  }
}

// ---------------- chunk scan (levels 1 & 2) ----------------
__global__ __launch_bounds__(256) void k_chunkscan(
    const USHORT* __restrict__ Asrc, const float* __restrict__ dsrc,
    const float* __restrict__ Bsrc,
    USHORT* __restrict__ Mdst, float* __restrict__ vdst, int nsteps)
{
  __shared__ __align__(16) USHORT Abuf[2][128*128];
  __shared__ __align__(16) USHORT MT[2][128*136];   // MT[buf][j*136+k] = M[k][j]
  __shared__ float vbuf[2][128];
  __shared__ float dbuf[2][128];

  const int tid = threadIdx.x, lane = tid&63, wave = tid>>6;
  const int wr = wave>>1, wc = wave&1, l15 = lane&15, l4 = lane>>4;
  const size_t blk = blockIdx.x;

  for (int idx=tid; idx<2176; idx+=256) ((uint4*)&MT[0][0])[idx] = make_uint4(0,0,0,0);
  __syncthreads();
  if (tid<128){ MT[0][tid*136+tid] = 0x3F80; vbuf[0][tid] = 0.f; }

  f32x4 Mreg[4][4];
  #pragma unroll
  for (int r=0;r<4;r++){
    #pragma unroll
    for (int c=0;c<4;c++){
      #pragma unroll
      for (int q=0;q<4;q++){
        int i = wr*64+r*16+l4*4+q, j = wc*64+c*16+l15;
        Mreg[r][c][q] = (i==j) ? 1.f : 0.f;
      }
    }
  }

  const int xb16   = ((tid&15)^(tid>>4))<<4;
  const int rowoff = (tid>>4)*256;

  #define CS_STAGE(buf, t) do { \
    const char* _b = (const char*)Asrc + ((size_t)(blk*nsteps + (t))<<15); \
    _Pragma("unroll") \
    for (int j=0;j<8;j++) \
      glds16(_b + j*4096 + rowoff + xb16, (char*)&Abuf[buf][0] + j*4096 + wave*1024); \
    if (dsrc && tid<128) \
      glds4((const char*)(dsrc + (size_t)(blk*nsteps + (t))*128) + tid*4, \
            (char*)&dbuf[buf][0] + (tid>>6)*256); \
  } while(0)

  CS_STAGE(0, 0);
  __syncthreads();

  int cur = 0;
  for (int t=0; t<nsteps; ++t){
    const int nxt = cur^1;
    if (t+1 < nsteps) CS_STAGE(nxt, t+1);

    f32x4 pacc[4][4];
    #pragma unroll
    for (int r=0;r<4;r++){
      #pragma unroll
      for (int c=0;c<4;c++) pacc[r][c] = f32x4{0.f,0.f,0.f,0.f};
    }
    #pragma unroll
    for (int kb=0; kb<4; ++kb){
      s16x8 af[4], bfr[4];
      #pragma unroll
      for (int r=0;r<4;r++){
        const int ra = wr*64 + r*16 + l15;
        af[r] = *(const s16x8*)&Abuf[cur][ra*128 + (((kb*4+l4)^l15)<<3)];
      }
      #pragma unroll
      for (int c=0;c<4;c++) bfr[c] = *(const s16x8*)&MT[cur][(wc*64 + c*16 + l15)*136 + kb*32 + l4*8];
      #pragma unroll
      for (int r=0;r<4;r++){
        #pragma unroll
        for (int c=0;c<4;c++)
          pacc[r][c] = __builtin_amdgcn_mfma_f32_16x16x32_bf16(af[r], bfr[c], pacc[r][c], 0,0,0);
      }
    }
    if (dsrc){
      #pragma unroll
      for (int r=0;r<4;r++){
        const int ib = wr*64 + r*16 + l4*4;
        #pragma unroll
        for (int q=0;q<4;q++){
          const float dv = dbuf[cur][ib+q];
          #pragma unroll
          for (int c=0;c<4;c++) pacc[r][c][q] += dv * Mreg[r][c][q];
        }
      }
    }
    #pragma unroll
    for (int r=0;r<4;r++){
      const int ib = wr*64 + r*16 + l4*4;
      #pragma unroll
      for (int c=0;c<4;c++){
        const int j = wc*64 + c*16 + l15;
        USHORT o0 = f2bf(pacc[r][c][0]), o1 = f2bf(pacc[r][c][1]);
        USHORT o2 = f2bf(pacc[r][c][2]), o3 = f2bf(pacc[r][c][3]);
        *(uint2*)&MT[nxt][j*136 + ib] =
            make_uint2((unsigned)o0 | ((unsigned)o1<<16), (unsigned)o2 | ((unsigned)o3<<16));
        Mreg[r][c] = pacc[r][c];
      }
    }
    if (tid<128){
      float acc = 0.f;
      const float* hv = &vbuf[cur][0];
      #pragma unroll
      for (int kb2=0; kb2<16; ++kb2){
        uint4 av = *(const uint4*)&Abuf[cur][tid*128 + ((kb2^(tid&15))<<3)];
        float4 h0 = *(const float4*)(hv + kb2*8);
        float4 h1 = *(const float4*)(hv + kb2*8 + 4);
        acc += bflo(av.x)*h0.x + bfhi(av.x)*h0.y + bflo(av.y)*h0.z + bfhi(av.y)*h0.w
             + bflo(av.z)*h1.x + bfhi(av.z)*h1.y + bflo(av.w)*h1.z + bfhi(av.w)*h1.w;
      }
      if (dsrc) acc += dbuf[cur][tid]*vbuf[cur][tid];
      acc += Bsrc[(size_t)(blk*nsteps + t)*128 + tid];
      vbuf[nxt][tid] = acc;
    }
    __syncthreads();
    cur = nxt;
  }
  {
    USHORT* gm = Mdst + blk*16384;
    #pragma unroll
    for (int it=0; it<8; ++it){
      int flat = it*256 + tid;
      int i = flat>>4, k0 = (flat&15)<<3;
      USHORT tmp[8];
      #pragma unroll
      for (int e=0;e<8;e++) tmp[e] = MT[cur][(k0+e)*136 + i];
      uint4 o;
      o.x = (unsigned)tmp[0] | ((unsigned)tmp[1]<<16);
      o.y = (unsigned)tmp[2] | ((unsigned)tmp[3]<<16);
      o.z = (unsigned)tmp[4] | ((unsigned)tmp[5]<<16);
      o.w = (unsigned)tmp[6] | ((unsigned)tmp[7]<<16);
      *(uint4*)(gm + i*128 + k0) = o;
    }
    if (tid<128) vdst[blk*128 + tid] = vbuf[cur][tid];
  }
  #undef CS_STAGE
}

// ---------------- super scan (per slab) ----------------
__global__ __launch_bounds__(128) void k_superscan(const USHORT* __restrict__ Ms,
    const float* __restrict__ vs, float* __restrict__ hss, int spb)
{
  __shared__ float hl[128];
  int b = blockIdx.x, tid = threadIdx.x;
  hl[tid] = 0.f;
  __syncthreads();
  for (int s=0;s<spb;s++){
    size_t idx = (size_t)b*spb + s;
    hss[idx*128 + tid] = hl[tid];
    const USHORT* M = Ms + idx*16384 + (size_t)tid*128;
    float acc = 0.f;
    #pragma unroll
    for (int kb=0;kb<16;kb++){
      uint4 av = *(const uint4*)(M + kb*8);
      float4 h0 = *(const float4*)&hl[kb*8];
      float4 h1 = *(const float4*)&hl[kb*8+4];
      acc += bflo(av.x)*h0.x + bfhi(av.x)*h0.y + bflo(av.y)*h0.z + bfhi(av.y)*h0.w
           + bflo(av.z)*h1.x + bfhi(av.z)*h1.y + bflo(av.w)*h1.z + bfhi(av.w)*h1.w;
    }
    acc += vs[idx*128 + tid];
    __syncthreads();
    hl[tid] = acc;
    __syncthreads();
  }
}

// ---------------- chunk starts ----------------
__global__ __launch_bounds__(128) void k_chunkstarts(const USHORT* __restrict__ Mc,
    const float* __restrict__ vc, const float* __restrict__ hss, float* __restrict__ hcs)
{
  __shared__ float hl[128];
  int s = blockIdx.x, tid = threadIdx.x;
  hl[tid] = hss[(size_t)s*128 + tid];
  __syncthreads();
  for (int g=0; g<8; ++g){
    size_t c = (size_t)s*8 + g;
    hcs[c*128 + tid] = hl[tid];
    const USHORT* M = Mc + c*16384 + (size_t)tid*128;
    float acc = 0.f;
    #pragma unroll
    for (int kb=0;kb<16;kb++){
      uint4 av = *(const uint4*)(M + kb*8);
      float4 h0 = *(const float4*)&hl[kb*8];
      float4 h1 = *(const float4*)&hl[kb*8+4];
      acc += bflo(av.x)*h0.x + bfhi(av.x)*h0.y + bflo(av.y)*h0.z + bfhi(av.y)*h0.w
           + bflo(av.z)*h1.x + bfhi(av.z)*h1.y + bflo(av.w)*h1.z + bfhi(av.w)*h1.w;
    }
    acc += vc[c*128 + tid];
    __syncthreads();
    hl[tid] = acc;
    __syncthreads();
  }
}

// ---------------- phase 3: serial replay of chunk from its start state ----------------
__global__ __launch_bounds__(256) void k_phase3(
    const USHORT* __restrict__ Asrc, const float* __restrict__ dsrc,
    const float* __restrict__ Bsrc, const float* __restrict__ hcs,
    float* __restrict__ hs, int nsteps)
{
  __shared__ __align__(16) USHORT Abuf[2][128*128];
  __shared__ float hb[2][128];
  __shared__ float db[2][128];
  const int tid = threadIdx.x, wave = tid>>6;
  const size_t blk = blockIdx.x;
  const int xb16   = ((tid&15)^(tid>>4))<<4;
  const int rowoff = (tid>>4)*256;

  #define P3_STAGE(buf, t) do { \
    const char* _b = (const char*)Asrc + ((size_t)(blk*nsteps + (t))<<15); \
    _Pragma("unroll") \
    for (int j=0;j<8;j++) \
      glds16(_b + j*4096 + rowoff + xb16, (char*)&Abuf[buf][0] + j*4096 + wave*1024); \
    if (tid<128) \
      glds4((const char*)(dsrc + (size_t)(blk*nsteps + (t))*128) + tid*4, \
            (char*)&db[buf][0] + (tid>>6)*256); \
  } while(0)

  P3_STAGE(0, 0);
  if (tid<128) hb[0][tid] = hcs[blk*128 + tid];
  __syncthreads();

  int cur = 0;
  for (int t=0; t<nsteps; ++t){
    const int nxt = cur^1;
    if (t+1 < nsteps) P3_STAGE(nxt, t+1);
    if (tid<128){
      float acc = 0.f;
      const float* hv = &hb[cur][0];
      #pragma unroll
      for (int kb=0;kb<16;kb++){
        uint4 av = *(const uint4*)&Abuf[cur][tid*128 + ((kb^(tid&15))<<3)];
        float4 h0 = *(const float4*)(hv + kb*8);
        float4 h1 = *(const float4*)(hv + kb*8+4);
        acc += bflo(av.x)*h0.x + bfhi(av.x)*h0.y + bflo(av.y)*h0.z + bfhi(av.y)*h0.w
             + bflo(av.z)*h1.x + bfhi(av.z)*h1.y + bflo(av.w)*h1.z + bfhi(av.w)*h1.w;
      }
      acc += db[cur][tid]*hb[cur][tid];
      acc += Bsrc[(size_t)(blk*nsteps + t)*128 + tid];
      hs[(size_t)(blk*nsteps + t)*128 + tid] = acc;
      hb[nxt][tid] = acc;
    }
    __syncthreads();
    cur = nxt;
  }
  #undef P3_STAGE
}

// ---------------- output: y = hs @ C + D_skip * u ----------------
__global__ __launch_bounds__(256) void k_out(const float* __restrict__ hs,
    const float* __restrict__ Cm, const float* __restrict__ Dsk,
    const float* __restrict__ u, float* __restrict__ y)
{
  __shared__ float hsl[8][128];
  const int tid = threadIdx.x;
  const size_t tk0 = (size_t)blockIdx.x*8;
  for (int i=tid; i<1024; i+=256) hsl[i>>7][i&127] = hs[tk0*128 + i];
  __syncthreads();
  #pragma unroll
  for (int dc=0; dc<4; ++dc){
    const int d = dc*256 + tid;
    float a0=0,a1=0,a2=0,a3=0,a4=0,a5=0,a6=0,a7=0;
    for (int n=0;n<128;++n){
      float cv = Cm[(size_t)n*1024 + d];
      a0 += hsl[0][n]*cv; a1 += hsl[1][n]*cv; a2 += hsl[2][n]*cv; a3 += hsl[3][n]*cv;
      a4 += hsl[4][n]*cv; a5 += hsl[5][n]*cv; a6 += hsl[6][n]*cv; a7 += hsl[7][n]*cv;
    }
    float dd = Dsk[d];
    float av[8] = {a0,a1,a2,a3,a4,a5,a6,a7};
    #pragma unroll
    for (int tkk=0;tkk<8;tkk++){
      size_t idx = (tk0+tkk)*1024 + d;
      y[idx] = av[tkk] + dd*u[idx];
    }
  }
}

__global__ void k_report(float* out, float val){
  if (threadIdx.x==0 && blockIdx.x==0) out[0] = val;
}

extern "C" void kernel_launch(void* const* d_in, const int* in_sizes, int n_in,
                              void* d_out, int out_size, void* d_ws, size_t ws_size,
                              hipStream_t stream)
{
  const float* u   = (const float*)d_in[0];
  const float* Wd  = (const float*)d_in[1];
  const float* bd  = (const float*)d_in[2];
  const float* WA  = (const float*)d_in[3];
  const float* bA  = (const float*)d_in[4];
  const float* WB  = (const float*)d_in[5];
  const float* bB  = (const float*)d_in[6];
  const float* Cm  = (const float*)d_in[7];
  const float* Dsk = (const float*)d_in[8];
  float* y = (float*)d_out;
  (void)in_sizes; (void)n_in; (void)out_size;

  int NSLAB;
  if      (ws_size >= 208000000ull) NSLAB = 2;
  else if (ws_size >= 136000000ull) NSLAB = 4;
  else { k_report<<<1, 64, 0, stream>>>(y, (float)(ws_size >> 20)); return; }

  const int L = 16;
  const int rowsSlab   = 8192/NSLAB;
  const int cps        = rowsSlab/L;
  const int supersSlab = cps/8;
  const int batchSlab  = 4/NSLAB;

  char* w = (char*)d_ws;
  size_t off = 0;
  auto take = [&](size_t bytes)->char*{ char* p = w + off; off += (bytes+255)&~(size_t)255; return p; };
  USHORT* u_bf  = (USHORT*)take(8192ull*1024*2);
  USHORT* WAT   = (USHORT*)take(16384ull*1024*2);
  USHORT* W2    = (USHORT*)take(256ull*1024*2);
  float*  d_arr = (float*)take(8192ull*128*4);
  float*  Btv   = (float*)take(8192ull*128*4);
  USHORT* Amat  = (USHORT*)take((size_t)rowsSlab*16384*2);
  USHORT* Mc    = (USHORT*)take((size_t)cps*16384*2);
  float*  vc    = (float*)take((size_t)cps*128*4);
  USHORT* Ms    = (USHORT*)take((size_t)supersSlab*16384*2);
  float*  vs    = (float*)take((size_t)supersSlab*128*4);
  float*  hss   = (float*)take((size_t)supersSlab*128*4);
  float*  hcs   = (float*)take((size_t)cps*128*4);
  float*  hs    = (float*)take(8192ull*128*4);

  k_convert<<<2048, 256, 0, stream>>>(u, u_bf, 8192*1024/4);
  k_transpose<<<dim3(16,256), 256, 0, stream>>>(WA, WAT, 1024, 16384);
  k_transpose<<<dim3(16,2), 256, 0, stream>>>(Wd, W2, 1024, 128);
  k_transpose<<<dim3(16,2), 256, 0, stream>>>(WB, W2 + 128*1024, 1024, 128);
  k_gemmdb<<<dim3(64,2), 256, 0, stream>>>(u_bf, W2, bd, bB, d_arr, Btv, 1024);

  for (int s=0; s<NSLAB; ++s){
    const size_t r0 = (size_t)s*rowsSlab;
    k_gemm256<<<dim3(rowsSlab/256,64), 512, 0, stream>>>(u_bf + r0*1024, WAT, bA, Amat, 1024);
    k_chunkscan<<<cps, 256, 0, stream>>>(Amat, d_arr + r0*128, Btv + r0*128, Mc, vc, L);
    k_chunkscan<<<supersSlab, 256, 0, stream>>>(Mc, nullptr, vc, Ms, vs, 8);
    k_superscan<<<batchSlab, 128, 0, stream>>>(Ms, vs, hss, supersSlab/batchSlab);
    k_chunkstarts<<<supersSlab, 128, 0, stream>>>(Mc, vc, hss, hcs);
    k_phase3<<<cps, 256, 0, stream>>>(Amat, d_arr + r0*128, Btv + r0*128,
                                      hcs, hs + r0*128, L);
  }
  k_out<<<1024, 256, 0, stream>>>(hs, Cm, Dsk, u, y);
}

// Round 16
// 863.278 us; speedup vs baseline: 1.1024x; 1.1024x over previous
//
#include <hip/hip_runtime.h>

typedef __attribute__((ext_vector_type(4))) float f32x4;
typedef __attribute__((ext_vector_type(8))) short s16x8;
typedef __attribute__((ext_vector_type(4))) unsigned int u32x4;
typedef unsigned short USHORT;

static __device__ __forceinline__ USHORT f2bf(float f){
  unsigned u = __float_as_uint(f);
  u += 0x7FFFu + ((u>>16)&1u);
  return (USHORT)(u>>16);
}
static __device__ __forceinline__ float bflo(unsigned u){ return __uint_as_float(u<<16); }
static __device__ __forceinline__ float bfhi(unsigned u){ return __uint_as_float(u & 0xFFFF0000u); }

static __device__ __forceinline__ void glds16(const void* g, void* l){
  typedef __attribute__((address_space(1))) const unsigned int guint;
  typedef __attribute__((address_space(3))) unsigned int luint;
  __builtin_amdgcn_global_load_lds((guint*)g, (luint*)l, 16, 0, 0);
}
static __device__ __forceinline__ void glds4(const void* g, void* l){
  typedef __attribute__((address_space(1))) const unsigned int guint;
  typedef __attribute__((address_space(3))) unsigned int luint;
  __builtin_amdgcn_global_load_lds((guint*)g, (luint*)l, 4, 0, 0);
}

// ---------------- fp32 -> bf16 convert ----------------
__global__ void k_convert(const float* __restrict__ src, USHORT* __restrict__ dst, int n4){
  for (int i = blockIdx.x*blockDim.x + threadIdx.x; i < n4; i += gridDim.x*blockDim.x){
    float4 v = ((const float4*)src)[i];
    ushort4 o; o.x=f2bf(v.x); o.y=f2bf(v.y); o.z=f2bf(v.z); o.w=f2bf(v.w);
    ((ushort4*)dst)[i] = o;
  }
}

// ---------------- transpose+convert: src fp32 [K][N] -> dst bf16 [N][K] ----------------
__global__ __launch_bounds__(256) void k_transpose(const float* __restrict__ src,
    USHORT* __restrict__ dst, int K, int N)
{
  __shared__ float tile[64][65];
  int tx = threadIdx.x & 15, ty = threadIdx.x >> 4;
  size_t k0 = (size_t)blockIdx.x*64, n0 = (size_t)blockIdx.y*64;
  #pragma unroll
  for (int j=0;j<4;j++){
    int row = j*16 + ty;
    float4 v = *(const float4*)&src[(k0+row)*(size_t)N + n0 + tx*4];
    tile[row][tx*4+0] = v.x; tile[row][tx*4+1] = v.y;
    tile[row][tx*4+2] = v.z; tile[row][tx*4+3] = v.w;
  }
  __syncthreads();
  #pragma unroll
  for (int j=0;j<4;j++){
    int nn = j*16 + ty;
    ushort4 o;
    o.x = f2bf(tile[tx*4+0][nn]);
    o.y = f2bf(tile[tx*4+1][nn]);
    o.z = f2bf(tile[tx*4+2][nn]);
    o.w = f2bf(tile[tx*4+3][nn]);
    *(ushort4*)&dst[(n0+nn)*(size_t)K + k0 + tx*4] = o;
  }
}

// ---------------- 256x256 BK=64 8-wave GEMM, register-pipelined frags (r12 best) -------
// One __syncthreads per K-tile; 8 next-tile glds16 issued right after; read/MFMA chain
// compiler-scheduled (fine lgkmcnt) so ds_reads of step p+1 overlap MFMAs of step p.
__global__ __launch_bounds__(512, 1) void k_gemm256(const USHORT* __restrict__ A,
    const USHORT* __restrict__ B, const float* __restrict__ bias,
    USHORT* __restrict__ outA, int K)
{
  __shared__ __align__(16) char smem[131072];
  const int tid = threadIdx.x, lane = tid&63, wave = tid>>6;
  const int wr = wave>>2, wc = wave&3, l15 = lane&15, l4 = lane>>4;

  const int gx = gridDim.x;
  int flatb = blockIdx.y*gx + blockIdx.x;
  int nwg  = gx*gridDim.y;
  int swz  = (flatb & 7)*(nwg>>3) + (flatb>>3);
  const size_t m0 = (size_t)(swz % gx)*256, n0 = (size_t)(swz / gx)*256;

  f32x4 acc[8][4];
  #pragma unroll
  for (int r=0;r<8;r++){
    #pragma unroll
    for (int c=0;c<4;c++) acc[r][c] = f32x4{0.f,0.f,0.f,0.f};
  }
  const int nk = K>>6;

  const char* Abase = (const char*)A + ((m0*(size_t)K)<<1);
  const char* Bbase = (const char*)B + ((n0*(size_t)K)<<1);
  unsigned aro[4];
  #pragma unroll
  for (int q=0;q<4;q++){
    const int idx = q*512 + tid;
    const int row = idx>>3, blk = idx&7;
    aro[q] = ((unsigned)(row*K)<<1) + (unsigned)((blk^(row&7))<<4);
  }

  #define SG_A(buf, kt, q) glds16(Abase + aro[q] + ((unsigned)(kt)<<7), \
                                  smem + (buf)*32768 + (q)*8192 + tid*16)
  #define SG_B(buf, kt, q) glds16(Bbase + aro[q] + ((unsigned)(kt)<<7), \
                                  smem + 65536 + (buf)*32768 + (q)*8192 + tid*16)

  #pragma unroll
  for (int q=0;q<4;q++) SG_A(0,0,q);
  #pragma unroll
  for (int q=0;q<4;q++) SG_B(0,0,q);

  for (int kt=0; kt<nk; ++kt){
    const int cur = kt&1, nxt = cur^1;
    __syncthreads();   // vmcnt(0)+barrier: cur's stages visible to all waves
    if (kt+1 < nk){
      #pragma unroll
      for (int q=0;q<4;q++) SG_A(nxt, kt+1, q);
      #pragma unroll
      for (int q=0;q<4;q++) SG_B(nxt, kt+1, q);
    }
    const USHORT* Ab = (const USHORT*)(smem + cur*32768);
    const USHORT* Bb = (const USHORT*)(smem + 65536 + cur*32768);
    s16x8 afA[4], afB[4], afC[4], afD[4], bf0[4], bf1[4];
    // kb0 reads
    #pragma unroll
    for (int mm=0;mm<4;mm++){
      const int rowa = wr*128 + mm*16 + l15;
      afA[mm] = *(const s16x8*)&Ab[rowa*64 + (((0*4+l4)^(rowa&7))<<3)];
    }
    #pragma unroll
    for (int n=0;n<4;n++){
      const int rowb = wc*64 + n*16 + l15;
      bf0[n] = *(const s16x8*)&Bb[rowb*64 + (((0*4+l4)^(rowb&7))<<3)];
    }
    #pragma unroll
    for (int mm=0;mm<4;mm++){
      const int rowa = wr*128 + 64 + mm*16 + l15;
      afB[mm] = *(const s16x8*)&Ab[rowa*64 + (((0*4+l4)^(rowa&7))<<3)];
    }
    // MFMA kb0 mh0
    #pragma unroll
    for (int mm=0;mm<4;mm++){
      #pragma unroll
      for (int n=0;n<4;n++)
        acc[mm][n] = __builtin_amdgcn_mfma_f32_16x16x32_bf16(afA[mm], bf0[n], acc[mm][n], 0,0,0);
    }
    // kb1 reads (mh0 + B)
    #pragma unroll
    for (int mm=0;mm<4;mm++){
      const int rowa = wr*128 + mm*16 + l15;
      afC[mm] = *(const s16x8*)&Ab[rowa*64 + (((1*4+l4)^(rowa&7))<<3)];
    }
    #pragma unroll
    for (int n=0;n<4;n++){
      const int rowb = wc*64 + n*16 + l15;
      bf1[n] = *(const s16x8*)&Bb[rowb*64 + (((1*4+l4)^(rowb&7))<<3)];
    }
    // MFMA kb0 mh1
    #pragma unroll
    for (int mm=0;mm<4;mm++){
      #pragma unroll
      for (int n=0;n<4;n++)
        acc[4+mm][n] = __builtin_amdgcn_mfma_f32_16x16x32_bf16(afB[mm], bf0[n], acc[4+mm][n], 0,0,0);
    }
    // kb1 mh1 reads
    #pragma unroll
    for (int mm=0;mm<4;mm++){
      const int rowa = wr*128 + 64 + mm*16 + l15;
      afD[mm] = *(const s16x8*)&Ab[rowa*64 + (((1*4+l4)^(rowa&7))<<3)];
    }
    // MFMA kb1 mh0
    #pragma unroll
    for (int mm=0;mm<4;mm++){
      #pragma unroll
      for (int n=0;n<4;n++)
        acc[mm][n] = __builtin_amdgcn_mfma_f32_16x16x32_bf16(afC[mm], bf1[n], acc[mm][n], 0,0,0);
    }
    // MFMA kb1 mh1
    #pragma unroll
    for (int mm=0;mm<4;mm++){
      #pragma unroll
      for (int n=0;n<4;n++)
        acc[4+mm][n] = __builtin_amdgcn_mfma_f32_16x16x32_bf16(afD[mm], bf1[n], acc[4+mm][n], 0,0,0);
    }
  }
  #undef SG_A
  #undef SG_B

  // epilogue: LDS-staged Ct [256][256] bf16 (16B-block swizzle), full-line nt stores
  __syncthreads();
  USHORT* Ct = (USHORT*)smem;
  float bvals[4];
  #pragma unroll
  for (int n=0;n<4;n++) bvals[n] = bias[n0 + wc*64 + n*16 + l15];
  #pragma unroll
  for (int mf=0;mf<8;mf++){
    #pragma unroll
    for (int n=0;n<4;n++){
      const int col = wc*64 + n*16 + l15;
      const size_t gc = n0 + col;
      const bool diag = ((int)(gc>>7) == (int)(gc&127));
      #pragma unroll
      for (int q=0;q<4;q++){
        const int rr = wr*128 + (mf<4 ? mf*16 : 64 + (mf-4)*16) + l4*4 + q;
        float v = acc[mf][n][q] + bvals[n];
        float e = exp2f(v * 2.885390081777927f);
        float tnh = 1.0f - 2.0f/(e + 1.0f);
        tnh = diag ? 0.0f : tnh*0.08838834764831845f;
        Ct[rr*256 + (((col>>3)^(rr&7))<<3) + (col&7)] = f2bf(tnh);
      }
    }
  }
  __syncthreads();
  #pragma unroll
  for (int it=0; it<16; ++it){
    const int flat = it*512 + tid;
    const int row = flat>>5, blk = flat&31;
    const int phys = blk ^ (row&7);
    u32x4 v = *(const u32x4*)&Ct[row*256 + (phys<<3)];
    __builtin_nontemporal_store(v, (u32x4*)(outA + (m0+row)*16384 + n0 + blk*8));
  }
}

// ---------------- small GEMM (d & B projections) ----------
__global__ __launch_bounds__(256) void k_gemmdb(const USHORT* __restrict__ A,
    const USHORT* __restrict__ B, const float* __restrict__ bias,
    const float* __restrict__ bias2,
    float* __restrict__ outd, float* __restrict__ outB, int K)
{
  __shared__ __align__(16) char smem[32768];
  const int tid = threadIdx.x, lane = tid&63, wave = tid>>6;
  const int wr = wave>>1, wc = wave&1, l15 = lane&15, l4 = lane>>4;
  const size_t m0 = (size_t)blockIdx.x*128, n0 = (size_t)blockIdx.y*128;

  f32x4 acc[4][4];
  #pragma unroll
  for (int r=0;r<4;r++){
    #pragma unroll
    for (int c=0;c<4;c++) acc[r][c] = f32x4{0.f,0.f,0.f,0.f};
  }
  const int nk = K>>5;
  const int srow = tid>>2; const int skb = (tid&3)*16;

  #define GSTAGE(buf, kt) do { \
    _Pragma("unroll") \
    for (int j=0;j<2;j++){ \
      glds16((const char*)A + ((m0 + j*64 + srow)*(size_t)K + (size_t)(kt)*32)*2 + skb, \
             smem + (buf)*8192 + j*4096 + wave*1024); \
      glds16((const char*)B + ((n0 + j*64 + srow)*(size_t)K + (size_t)(kt)*32)*2 + skb, \
             smem + 16384 + (buf)*8192 + j*4096 + wave*1024); \
    } \
  } while(0)

  GSTAGE(0, 0);
  GSTAGE(1, 1);
  for (int kt=0; kt<nk; ++kt){
    const int cur = kt&1;
    if (kt+1 < nk) asm volatile("s_waitcnt vmcnt(4)" ::: "memory");
    else           asm volatile("s_waitcnt vmcnt(0)" ::: "memory");
    __builtin_amdgcn_s_barrier();
    const USHORT* At = (const USHORT*)(smem + cur*8192);
    const USHORT* Bt = (const USHORT*)(smem + 16384 + cur*8192);
    s16x8 af[4], bf[4];
    #pragma unroll
    for (int r=0;r<4;r++) af[r] = *(const s16x8*)&At[(wr*64 + r*16 + l15)*32 + l4*8];
    #pragma unroll
    for (int c=0;c<4;c++) bf[c] = *(const s16x8*)&Bt[(wc*64 + c*16 + l15)*32 + l4*8];
    #pragma unroll
    for (int r=0;r<4;r++){
      #pragma unroll
      for (int c=0;c<4;c++)
        acc[r][c] = __builtin_amdgcn_mfma_f32_16x16x32_bf16(af[r], bf[c], acc[r][c], 0,0,0);
    }
    __builtin_amdgcn_s_barrier();
    if (kt+2 < nk) GSTAGE(cur, kt+2);
  }
  #undef GSTAGE

  #pragma unroll
  for (int r=0;r<4;r++){
    const int rowb = wr*64 + r*16 + l4*4;
    #pragma unroll
    for (int c=0;c<4;c++){
      const size_t gc = n0 + wc*64 + c*16 + l15;
      #pragma unroll
      for (int q=0;q<4;q++){
        const size_t grow = m0 + rowb + q;
        float v = acc[r][c][q];
        if ((int)gc < 128){
          float sgm = v + bias[gc];
          float e = exp2f(-sgm * 1.4426950408889634f);
          outd[grow*128 + gc] = 1.0f/(1.0f + e);
        } else {
          outB[grow*128 + (gc-128)] = v + bias2[gc-128];
        }
      }
    }
  }
}

// ---------------- chunk scan (levels 1 & 2) ----------------
__global__ __launch_bounds__(256) void k_chunkscan(
    const USHORT* __restrict__ Asrc, const float* __restrict__ dsrc,
    const float* __restrict__ Bsrc,
    USHORT* __restrict__ Mdst, float* __restrict__ vdst, int nsteps)
{
  __shared__ __align__(16) USHORT Abuf[2][128*128];
  __shared__ __align__(16) USHORT MT[2][128*136];   // MT[buf][j*136+k] = M[k][j]
  __shared__ float vbuf[2][128];
  __shared__ float dbuf[2][128];

  const int tid = threadIdx.x, lane = tid&63, wave = tid>>6;
  const int wr = wave>>1, wc = wave&1, l15 = lane&15, l4 = lane>>4;
  const size_t blk = blockIdx.x;

  for (int idx=tid; idx<2176; idx+=256) ((uint4*)&MT[0][0])[idx] = make_uint4(0,0,0,0);
  __syncthreads();
  if (tid<128){ MT[0][tid*136+tid] = 0x3F80; vbuf[0][tid] = 0.f; }

  f32x4 Mreg[4][4];
  #pragma unroll
  for (int r=0;r<4;r++){
    #pragma unroll
    for (int c=0;c<4;c++){
      #pragma unroll
      for (int q=0;q<4;q++){
        int i = wr*64+r*16+l4*4+q, j = wc*64+c*16+l15;
        Mreg[r][c][q] = (i==j) ? 1.f : 0.f;
      }
    }
  }

  const int xb16   = ((tid&15)^(tid>>4))<<4;
  const int rowoff = (tid>>4)*256;

  #define CS_STAGE(buf, t) do { \
    const char* _b = (const char*)Asrc + ((size_t)(blk*nsteps + (t))<<15); \
    _Pragma("unroll") \
    for (int j=0;j<8;j++) \
      glds16(_b + j*4096 + rowoff + xb16, (char*)&Abuf[buf][0] + j*4096 + wave*1024); \
    if (dsrc && tid<128) \
      glds4((const char*)(dsrc + (size_t)(blk*nsteps + (t))*128) + tid*4, \
            (char*)&dbuf[buf][0] + (tid>>6)*256); \
  } while(0)

  CS_STAGE(0, 0);
  __syncthreads();

  int cur = 0;
  for (int t=0; t<nsteps; ++t){
    const int nxt = cur^1;
    if (t+1 < nsteps) CS_STAGE(nxt, t+1);

    f32x4 pacc[4][4];
    #pragma unroll
    for (int r=0;r<4;r++){
      #pragma unroll
      for (int c=0;c<4;c++) pacc[r][c] = f32x4{0.f,0.f,0.f,0.f};
    }
    #pragma unroll
    for (int kb=0; kb<4; ++kb){
      s16x8 af[4], bfr[4];
      #pragma unroll
      for (int r=0;r<4;r++){
        const int ra = wr*64 + r*16 + l15;
        af[r] = *(const s16x8*)&Abuf[cur][ra*128 + (((kb*4+l4)^l15)<<3)];
      }
      #pragma unroll
      for (int c=0;c<4;c++) bfr[c] = *(const s16x8*)&MT[cur][(wc*64 + c*16 + l15)*136 + kb*32 + l4*8];
      #pragma unroll
      for (int r=0;r<4;r++){
        #pragma unroll
        for (int c=0;c<4;c++)
          pacc[r][c] = __builtin_amdgcn_mfma_f32_16x16x32_bf16(af[r], bfr[c], pacc[r][c], 0,0,0);
      }
    }
    if (dsrc){
      #pragma unroll
      for (int r=0;r<4;r++){
        const int ib = wr*64 + r*16 + l4*4;
        #pragma unroll
        for (int q=0;q<4;q++){
          const float dv = dbuf[cur][ib+q];
          #pragma unroll
          for (int c=0;c<4;c++) pacc[r][c][q] += dv * Mreg[r][c][q];
        }
      }
    }
    #pragma unroll
    for (int r=0;r<4;r++){
      const int ib = wr*64 + r*16 + l4*4;
      #pragma unroll
      for (int c=0;c<4;c++){
        const int j = wc*64 + c*16 + l15;
        USHORT o0 = f2bf(pacc[r][c][0]), o1 = f2bf(pacc[r][c][1]);
        USHORT o2 = f2bf(pacc[r][c][2]), o3 = f2bf(pacc[r][c][3]);
        *(uint2*)&MT[nxt][j*136 + ib] =
            make_uint2((unsigned)o0 | ((unsigned)o1<<16), (unsigned)o2 | ((unsigned)o3<<16));
        Mreg[r][c] = pacc[r][c];
      }
    }
    if (tid<128){
      float acc = 0.f;
      const float* hv = &vbuf[cur][0];
      #pragma unroll
      for (int kb2=0; kb2<16; ++kb2){
        uint4 av = *(const uint4*)&Abuf[cur][tid*128 + ((kb2^(tid&15))<<3)];
        float4 h0 = *(const float4*)(hv + kb2*8);
        float4 h1 = *(const float4*)(hv + kb2*8 + 4);
        acc += bflo(av.x)*h0.x + bfhi(av.x)*h0.y + bflo(av.y)*h0.z + bfhi(av.y)*h0.w
             + bflo(av.z)*h1.x + bfhi(av.z)*h1.y + bflo(av.w)*h1.z + bfhi(av.w)*h1.w;
      }
      if (dsrc) acc += dbuf[cur][tid]*vbuf[cur][tid];
      acc += Bsrc[(size_t)(blk*nsteps + t)*128 + tid];
      vbuf[nxt][tid] = acc;
    }
    __syncthreads();
    cur = nxt;
  }
  {
    USHORT* gm = Mdst + blk*16384;
    #pragma unroll
    for (int it=0; it<8; ++it){
      int flat = it*256 + tid;
      int i = flat>>4, k0 = (flat&15)<<3;
      USHORT tmp[8];
      #pragma unroll
      for (int e=0;e<8;e++) tmp[e] = MT[cur][(k0+e)*136 + i];
      uint4 o;
      o.x = (unsigned)tmp[0] | ((unsigned)tmp[1]<<16);
      o.y = (unsigned)tmp[2] | ((unsigned)tmp[3]<<16);
      o.z = (unsigned)tmp[4] | ((unsigned)tmp[5]<<16);
      o.w = (unsigned)tmp[6] | ((unsigned)tmp[7]<<16);
      *(uint4*)(gm + i*128 + k0) = o;
    }
    if (tid<128) vdst[blk*128 + tid] = vbuf[cur][tid];
  }
  #undef CS_STAGE
}

// ---------------- super scan (per slab) ----------------
__global__ __launch_bounds__(128) void k_superscan(const USHORT* __restrict__ Ms,
    const float* __restrict__ vs, float* __restrict__ hss, int spb)
{
  __shared__ float hl[128];
  int b = blockIdx.x, tid = threadIdx.x;
  hl[tid] = 0.f;
  __syncthreads();
  for (int s=0;s<spb;s++){
    size_t idx = (size_t)b*spb + s;
    hss[idx*128 + tid] = hl[tid];
    const USHORT* M = Ms + idx*16384 + (size_t)tid*128;
    float acc = 0.f;
    #pragma unroll
    for (int kb=0;kb<16;kb++){
      uint4 av = *(const uint4*)(M + kb*8);
      float4 h0 = *(const float4*)&hl[kb*8];
      float4 h1 = *(const float4*)&hl[kb*8+4];
      acc += bflo(av.x)*h0.x + bfhi(av.x)*h0.y + bflo(av.y)*h0.z + bfhi(av.y)*h0.w
           + bflo(av.z)*h1.x + bfhi(av.z)*h1.y + bflo(av.w)*h1.z + bfhi(av.w)*h1.w;
    }
    acc += vs[idx*128 + tid];
    __syncthreads();
    hl[tid] = acc;
    __syncthreads();
  }
}

// ---------------- chunk starts ----------------
__global__ __launch_bounds__(128) void k_chunkstarts(const USHORT* __restrict__ Mc,
    const float* __restrict__ vc, const float* __restrict__ hss, float* __restrict__ hcs)
{
  __shared__ float hl[128];
  int s = blockIdx.x, tid = threadIdx.x;
  hl[tid] = hss[(size_t)s*128 + tid];
  __syncthreads();
  for (int g=0; g<8; ++g){
    size_t c = (size_t)s*8 + g;
    hcs[c*128 + tid] = hl[tid];
    const USHORT* M = Mc + c*16384 + (size_t)tid*128;
    float acc = 0.f;
    #pragma unroll
    for (int kb=0;kb<16;kb++){
      uint4 av = *(const uint4*)(M + kb*8);
      float4 h0 = *(const float4*)&hl[kb*8];
      float4 h1 = *(const float4*)&hl[kb*8+4];
      acc += bflo(av.x)*h0.x + bfhi(av.x)*h0.y + bflo(av.y)*h0.z + bfhi(av.y)*h0.w
           + bflo(av.z)*h1.x + bfhi(av.z)*h1.y + bflo(av.w)*h1.z + bfhi(av.w)*h1.w;
    }
    acc += vc[c*128 + tid];
    __syncthreads();
    hl[tid] = acc;
    __syncthreads();
  }
}

// ---------------- phase 3: serial replay of chunk from its start state ----------------
__global__ __launch_bounds__(256) void k_phase3(
    const USHORT* __restrict__ Asrc, const float* __restrict__ dsrc,
    const float* __restrict__ Bsrc, const float* __restrict__ hcs,
    float* __restrict__ hs, int nsteps)
{
  __shared__ __align__(16) USHORT Abuf[2][128*128];
  __shared__ float hb[2][128];
  __shared__ float db[2][128];
  const int tid = threadIdx.x, wave = tid>>6;
  const size_t blk = blockIdx.x;
  const int xb16   = ((tid&15)^(tid>>4))<<4;
  const int rowoff = (tid>>4)*256;

  #define P3_STAGE(buf, t) do { \
    const char* _b = (const char*)Asrc + ((size_t)(blk*nsteps + (t))<<15); \
    _Pragma("unroll") \
    for (int j=0;j<8;j++) \
      glds16(_b + j*4096 + rowoff + xb16, (char*)&Abuf[buf][0] + j*4096 + wave*1024); \
    if (tid<128) \
      glds4((const char*)(dsrc + (size_t)(blk*nsteps + (t))*128) + tid*4, \
            (char*)&db[buf][0] + (tid>>6)*256); \
  } while(0)

  P3_STAGE(0, 0);
  if (tid<128) hb[0][tid] = hcs[blk*128 + tid];
  __syncthreads();

  int cur = 0;
  for (int t=0; t<nsteps; ++t){
    const int nxt = cur^1;
    if (t+1 < nsteps) P3_STAGE(nxt, t+1);
    if (tid<128){
      float acc = 0.f;
      const float* hv = &hb[cur][0];
      #pragma unroll
      for (int kb=0;kb<16;kb++){
        uint4 av = *(const uint4*)&Abuf[cur][tid*128 + ((kb^(tid&15))<<3)];
        float4 h0 = *(const float4*)(hv + kb*8);
        float4 h1 = *(const float4*)(hv + kb*8+4);
        acc += bflo(av.x)*h0.x + bfhi(av.x)*h0.y + bflo(av.y)*h0.z + bfhi(av.y)*h0.w
             + bflo(av.z)*h1.x + bfhi(av.z)*h1.y + bflo(av.w)*h1.z + bfhi(av.w)*h1.w;
      }
      acc += db[cur][tid]*hb[cur][tid];
      acc += Bsrc[(size_t)(blk*nsteps + t)*128 + tid];
      hs[(size_t)(blk*nsteps + t)*128 + tid] = acc;
      hb[nxt][tid] = acc;
    }
    __syncthreads();
    cur = nxt;
  }
  #undef P3_STAGE
}

// ---------------- output: y = hs @ C + D_skip * u ----------------
__global__ __launch_bounds__(256) void k_out(const float* __restrict__ hs,
    const float* __restrict__ Cm, const float* __restrict__ Dsk,
    const float* __restrict__ u, float* __restrict__ y)
{
  __shared__ float hsl[8][128];
  const int tid = threadIdx.x;
  const size_t tk0 = (size_t)blockIdx.x*8;
  for (int i=tid; i<1024; i+=256) hsl[i>>7][i&127] = hs[tk0*128 + i];
  __syncthreads();
  #pragma unroll
  for (int dc=0; dc<4; ++dc){
    const int d = dc*256 + tid;
    float a0=0,a1=0,a2=0,a3=0,a4=0,a5=0,a6=0,a7=0;
    for (int n=0;n<128;++n){
      float cv = Cm[(size_t)n*1024 + d];
      a0 += hsl[0][n]*cv; a1 += hsl[1][n]*cv; a2 += hsl[2][n]*cv; a3 += hsl[3][n]*cv;
      a4 += hsl[4][n]*cv; a5 += hsl[5][n]*cv; a6 += hsl[6][n]*cv; a7 += hsl[7][n]*cv;
    }
    float dd = Dsk[d];
    float av[8] = {a0,a1,a2,a3,a4,a5,a6,a7};
    #pragma unroll
    for (int tkk=0;tkk<8;tkk++){
      size_t idx = (tk0+tkk)*1024 + d;
      y[idx] = av[tkk] + dd*u[idx];
    }
  }
}

__global__ void k_report(float* out, float val){
  if (threadIdx.x==0 && blockIdx.x==0) out[0] = val;
}

extern "C" void kernel_launch(void* const* d_in, const int* in_sizes, int n_in,
                              void* d_out, int out_size, void* d_ws, size_t ws_size,
                              hipStream_t stream)
{
  const float* u   = (const float*)d_in[0];
  const float* Wd  = (const float*)d_in[1];
  const float* bd  = (const float*)d_in[2];
  const float* WA  = (const float*)d_in[3];
  const float* bA  = (const float*)d_in[4];
  const float* WB  = (const float*)d_in[5];
  const float* bB  = (const float*)d_in[6];
  const float* Cm  = (const float*)d_in[7];
  const float* Dsk = (const float*)d_in[8];
  float* y = (float*)d_out;
  (void)in_sizes; (void)n_in; (void)out_size;

  int NSLAB;
  if      (ws_size >= 208000000ull) NSLAB = 2;
  else if (ws_size >= 136000000ull) NSLAB = 4;
  else { k_report<<<1, 64, 0, stream>>>(y, (float)(ws_size >> 20)); return; }

  const int L = 16;
  const int rowsSlab   = 8192/NSLAB;
  const int cps        = rowsSlab/L;
  const int supersSlab = cps/8;
  const int batchSlab  = 4/NSLAB;

  char* w = (char*)d_ws;
  size_t off = 0;
  auto take = [&](size_t bytes)->char*{ char* p = w + off; off += (bytes+255)&~(size_t)255; return p; };
  USHORT* u_bf  = (USHORT*)take(8192ull*1024*2);
  USHORT* WAT   = (USHORT*)take(16384ull*1024*2);
  USHORT* W2    = (USHORT*)take(256ull*1024*2);
  float*  d_arr = (float*)take(8192ull*128*4);
  float*  Btv   = (float*)take(8192ull*128*4);
  USHORT* Amat  = (USHORT*)take((size_t)rowsSlab*16384*2);
  USHORT* Mc    = (USHORT*)take((size_t)cps*16384*2);
  float*  vc    = (float*)take((size_t)cps*128*4);
  USHORT* Ms    = (USHORT*)take((size_t)supersSlab*16384*2);
  float*  vs    = (float*)take((size_t)supersSlab*128*4);
  float*  hss   = (float*)take((size_t)supersSlab*128*4);
  float*  hcs   = (float*)take((size_t)cps*128*4);
  float*  hs    = (float*)take(8192ull*128*4);

  k_convert<<<2048, 256, 0, stream>>>(u, u_bf, 8192*1024/4);
  k_transpose<<<dim3(16,256), 256, 0, stream>>>(WA, WAT, 1024, 16384);
  k_transpose<<<dim3(16,2), 256, 0, stream>>>(Wd, W2, 1024, 128);
  k_transpose<<<dim3(16,2), 256, 0, stream>>>(WB, W2 + 128*1024, 1024, 128);
  k_gemmdb<<<dim3(64,2), 256, 0, stream>>>(u_bf, W2, bd, bB, d_arr, Btv, 1024);

  for (int s=0; s<NSLAB; ++s){
    const size_t r0 = (size_t)s*rowsSlab;
    k_gemm256<<<dim3(rowsSlab/256,64), 512, 0, stream>>>(u_bf + r0*1024, WAT, bA, Amat, 1024);
    k_chunkscan<<<cps, 256, 0, stream>>>(Amat, d_arr + r0*128, Btv + r0*128, Mc, vc, L);
    k_chunkscan<<<supersSlab, 256, 0, stream>>>(Mc, nullptr, vc, Ms, vs, 8);
    k_superscan<<<batchSlab, 128, 0, stream>>>(Ms, vs, hss, supersSlab/batchSlab);
    k_chunkstarts<<<supersSlab, 128, 0, stream>>>(Mc, vc, hss, hcs);
    k_phase3<<<cps, 256, 0, stream>>>(Amat, d_arr + r0*128, Btv + r0*128,
                                      hcs, hs + r0*128, L);
  }
  k_out<<<1024, 256, 0, stream>>>(hs, Cm, Dsk, u, y);
}

// Round 17
// 837.087 us; speedup vs baseline: 1.1369x; 1.0313x over previous
//
#include <hip/hip_runtime.h>

typedef __attribute__((ext_vector_type(4))) float f32x4;
typedef __attribute__((ext_vector_type(8))) short s16x8;
typedef __attribute__((ext_vector_type(4))) unsigned int u32x4;
typedef unsigned short USHORT;

static __device__ __forceinline__ USHORT f2bf(float f){
  unsigned u = __float_as_uint(f);
  u += 0x7FFFu + ((u>>16)&1u);
  return (USHORT)(u>>16);
}
static __device__ __forceinline__ float bflo(unsigned u){ return __uint_as_float(u<<16); }
static __device__ __forceinline__ float bfhi(unsigned u){ return __uint_as_float(u & 0xFFFF0000u); }

static __device__ __forceinline__ void glds16(const void* g, void* l){
  typedef __attribute__((address_space(1))) const unsigned int guint;
  typedef __attribute__((address_space(3))) unsigned int luint;
  __builtin_amdgcn_global_load_lds((guint*)g, (luint*)l, 16, 0, 0);
}
static __device__ __forceinline__ void glds4(const void* g, void* l){
  typedef __attribute__((address_space(1))) const unsigned int guint;
  typedef __attribute__((address_space(3))) unsigned int luint;
  __builtin_amdgcn_global_load_lds((guint*)g, (luint*)l, 4, 0, 0);
}

// ---------------- fp32 -> bf16 convert ----------------
__global__ void k_convert(const float* __restrict__ src, USHORT* __restrict__ dst, int n4){
  for (int i = blockIdx.x*blockDim.x + threadIdx.x; i < n4; i += gridDim.x*blockDim.x){
    float4 v = ((const float4*)src)[i];
    ushort4 o; o.x=f2bf(v.x); o.y=f2bf(v.y); o.z=f2bf(v.z); o.w=f2bf(v.w);
    ((ushort4*)dst)[i] = o;
  }
}

// ---------------- transpose+convert: src fp32 [K][N] -> dst bf16 [N][K] ----------------
__global__ __launch_bounds__(256) void k_transpose(const float* __restrict__ src,
    USHORT* __restrict__ dst, int K, int N)
{
  __shared__ float tile[64][65];
  int tx = threadIdx.x & 15, ty = threadIdx.x >> 4;
  size_t k0 = (size_t)blockIdx.x*64, n0 = (size_t)blockIdx.y*64;
  #pragma unroll
  for (int j=0;j<4;j++){
    int row = j*16 + ty;
    float4 v = *(const float4*)&src[(k0+row)*(size_t)N + n0 + tx*4];
    tile[row][tx*4+0] = v.x; tile[row][tx*4+1] = v.y;
    tile[row][tx*4+2] = v.z; tile[row][tx*4+3] = v.w;
  }
  __syncthreads();
  #pragma unroll
  for (int j=0;j<4;j++){
    int nn = j*16 + ty;
    ushort4 o;
    o.x = f2bf(tile[tx*4+0][nn]);
    o.y = f2bf(tile[tx*4+1][nn]);
    o.z = f2bf(tile[tx*4+2][nn]);
    o.w = f2bf(tile[tx*4+3][nn]);
    *(ushort4*)&dst[(n0+nn)*(size_t)K + k0 + tx*4] = o;
  }
}

// ---------------- 256x256 BK=64 8-wave GEMM, register-pipelined frags (r12 best) -------
// Changes vs r12: (1) setprio(1) around MFMA clusters (T5; role diversity exists since
// waves drift within the tile); (2) plain stores in epilogue (Amat < L3 -> leave it
// L3-resident for the immediately-following chunkscan read).
__global__ __launch_bounds__(512, 1) void k_gemm256(const USHORT* __restrict__ A,
    const USHORT* __restrict__ B, const float* __restrict__ bias,
    USHORT* __restrict__ outA, int K)
{
  __shared__ __align__(16) char smem[131072];
  const int tid = threadIdx.x, lane = tid&63, wave = tid>>6;
  const int wr = wave>>2, wc = wave&3, l15 = lane&15, l4 = lane>>4;

  const int gx = gridDim.x;
  int flatb = blockIdx.y*gx + blockIdx.x;
  int nwg  = gx*gridDim.y;
  int swz  = (flatb & 7)*(nwg>>3) + (flatb>>3);
  const size_t m0 = (size_t)(swz % gx)*256, n0 = (size_t)(swz / gx)*256;

  f32x4 acc[8][4];
  #pragma unroll
  for (int r=0;r<8;r++){
    #pragma unroll
    for (int c=0;c<4;c++) acc[r][c] = f32x4{0.f,0.f,0.f,0.f};
  }
  const int nk = K>>6;

  const char* Abase = (const char*)A + ((m0*(size_t)K)<<1);
  const char* Bbase = (const char*)B + ((n0*(size_t)K)<<1);
  unsigned aro[4];
  #pragma unroll
  for (int q=0;q<4;q++){
    const int idx = q*512 + tid;
    const int row = idx>>3, blk = idx&7;
    aro[q] = ((unsigned)(row*K)<<1) + (unsigned)((blk^(row&7))<<4);
  }

  #define SG_A(buf, kt, q) glds16(Abase + aro[q] + ((unsigned)(kt)<<7), \
                                  smem + (buf)*32768 + (q)*8192 + tid*16)
  #define SG_B(buf, kt, q) glds16(Bbase + aro[q] + ((unsigned)(kt)<<7), \
                                  smem + 65536 + (buf)*32768 + (q)*8192 + tid*16)

  #pragma unroll
  for (int q=0;q<4;q++) SG_A(0,0,q);
  #pragma unroll
  for (int q=0;q<4;q++) SG_B(0,0,q);

  for (int kt=0; kt<nk; ++kt){
    const int cur = kt&1, nxt = cur^1;
    __syncthreads();   // vmcnt(0)+barrier: cur's stages visible to all waves
    if (kt+1 < nk){
      #pragma unroll
      for (int q=0;q<4;q++) SG_A(nxt, kt+1, q);
      #pragma unroll
      for (int q=0;q<4;q++) SG_B(nxt, kt+1, q);
    }
    const USHORT* Ab = (const USHORT*)(smem + cur*32768);
    const USHORT* Bb = (const USHORT*)(smem + 65536 + cur*32768);
    s16x8 afA[4], afB[4], afC[4], afD[4], bf0[4], bf1[4];
    // kb0 reads
    #pragma unroll
    for (int mm=0;mm<4;mm++){
      const int rowa = wr*128 + mm*16 + l15;
      afA[mm] = *(const s16x8*)&Ab[rowa*64 + (((0*4+l4)^(rowa&7))<<3)];
    }
    #pragma unroll
    for (int n=0;n<4;n++){
      const int rowb = wc*64 + n*16 + l15;
      bf0[n] = *(const s16x8*)&Bb[rowb*64 + (((0*4+l4)^(rowb&7))<<3)];
    }
    #pragma unroll
    for (int mm=0;mm<4;mm++){
      const int rowa = wr*128 + 64 + mm*16 + l15;
      afB[mm] = *(const s16x8*)&Ab[rowa*64 + (((0*4+l4)^(rowa&7))<<3)];
    }
    // MFMA kb0 mh0
    __builtin_amdgcn_s_setprio(1);
    #pragma unroll
    for (int mm=0;mm<4;mm++){
      #pragma unroll
      for (int n=0;n<4;n++)
        acc[mm][n] = __builtin_amdgcn_mfma_f32_16x16x32_bf16(afA[mm], bf0[n], acc[mm][n], 0,0,0);
    }
    __builtin_amdgcn_s_setprio(0);
    // kb1 reads (mh0 + B)
    #pragma unroll
    for (int mm=0;mm<4;mm++){
      const int rowa = wr*128 + mm*16 + l15;
      afC[mm] = *(const s16x8*)&Ab[rowa*64 + (((1*4+l4)^(rowa&7))<<3)];
    }
    #pragma unroll
    for (int n=0;n<4;n++){
      const int rowb = wc*64 + n*16 + l15;
      bf1[n] = *(const s16x8*)&Bb[rowb*64 + (((1*4+l4)^(rowb&7))<<3)];
    }
    // MFMA kb0 mh1
    __builtin_amdgcn_s_setprio(1);
    #pragma unroll
    for (int mm=0;mm<4;mm++){
      #pragma unroll
      for (int n=0;n<4;n++)
        acc[4+mm][n] = __builtin_amdgcn_mfma_f32_16x16x32_bf16(afB[mm], bf0[n], acc[4+mm][n], 0,0,0);
    }
    __builtin_amdgcn_s_setprio(0);
    // kb1 mh1 reads
    #pragma unroll
    for (int mm=0;mm<4;mm++){
      const int rowa = wr*128 + 64 + mm*16 + l15;
      afD[mm] = *(const s16x8*)&Ab[rowa*64 + (((1*4+l4)^(rowa&7))<<3)];
    }
    // MFMA kb1 mh0
    __builtin_amdgcn_s_setprio(1);
    #pragma unroll
    for (int mm=0;mm<4;mm++){
      #pragma unroll
      for (int n=0;n<4;n++)
        acc[mm][n] = __builtin_amdgcn_mfma_f32_16x16x32_bf16(afC[mm], bf1[n], acc[mm][n], 0,0,0);
    }
    // MFMA kb1 mh1
    #pragma unroll
    for (int mm=0;mm<4;mm++){
      #pragma unroll
      for (int n=0;n<4;n++)
        acc[4+mm][n] = __builtin_amdgcn_mfma_f32_16x16x32_bf16(afD[mm], bf1[n], acc[4+mm][n], 0,0,0);
    }
    __builtin_amdgcn_s_setprio(0);
  }
  #undef SG_A
  #undef SG_B

  // epilogue: LDS-staged Ct [256][256] bf16 (16B-block swizzle), full-line plain stores
  __syncthreads();
  USHORT* Ct = (USHORT*)smem;
  float bvals[4];
  #pragma unroll
  for (int n=0;n<4;n++) bvals[n] = bias[n0 + wc*64 + n*16 + l15];
  #pragma unroll
  for (int mf=0;mf<8;mf++){
    #pragma unroll
    for (int n=0;n<4;n++){
      const int col = wc*64 + n*16 + l15;
      const size_t gc = n0 + col;
      const bool diag = ((int)(gc>>7) == (int)(gc&127));
      #pragma unroll
      for (int q=0;q<4;q++){
        const int rr = wr*128 + (mf<4 ? mf*16 : 64 + (mf-4)*16) + l4*4 + q;
        float v = acc[mf][n][q] + bvals[n];
        float e = exp2f(v * 2.885390081777927f);
        float tnh = 1.0f - 2.0f/(e + 1.0f);
        tnh = diag ? 0.0f : tnh*0.08838834764831845f;
        Ct[rr*256 + (((col>>3)^(rr&7))<<3) + (col&7)] = f2bf(tnh);
      }
    }
  }
  __syncthreads();
  #pragma unroll
  for (int it=0; it<16; ++it){
    const int flat = it*512 + tid;
    const int row = flat>>5, blk = flat&31;
    const int phys = blk ^ (row&7);
    u32x4 v = *(const u32x4*)&Ct[row*256 + (phys<<3)];
    *(u32x4*)(outA + (m0+row)*16384 + n0 + blk*8) = v;   // plain store: keep Amat in L3
  }
}

// ---------------- small GEMM (d & B projections) ----------
__global__ __launch_bounds__(256) void k_gemmdb(const USHORT* __restrict__ A,
    const USHORT* __restrict__ B, const float* __restrict__ bias,
    const float* __restrict__ bias2,
    float* __restrict__ outd, float* __restrict__ outB, int K)
{
  __shared__ __align__(16) char smem[32768];
  const int tid = threadIdx.x, lane = tid&63, wave = tid>>6;
  const int wr = wave>>1, wc = wave&1, l15 = lane&15, l4 = lane>>4;
  const size_t m0 = (size_t)blockIdx.x*128, n0 = (size_t)blockIdx.y*128;

  f32x4 acc[4][4];
  #pragma unroll
  for (int r=0;r<4;r++){
    #pragma unroll
    for (int c=0;c<4;c++) acc[r][c] = f32x4{0.f,0.f,0.f,0.f};
  }
  const int nk = K>>5;
  const int srow = tid>>2; const int skb = (tid&3)*16;

  #define GSTAGE(buf, kt) do { \
    _Pragma("unroll") \
    for (int j=0;j<2;j++){ \
      glds16((const char*)A + ((m0 + j*64 + srow)*(size_t)K + (size_t)(kt)*32)*2 + skb, \
             smem + (buf)*8192 + j*4096 + wave*1024); \
      glds16((const char*)B + ((n0 + j*64 + srow)*(size_t)K + (size_t)(kt)*32)*2 + skb, \
             smem + 16384 + (buf)*8192 + j*4096 + wave*1024); \
    } \
  } while(0)

  GSTAGE(0, 0);
  GSTAGE(1, 1);
  for (int kt=0; kt<nk; ++kt){
    const int cur = kt&1;
    if (kt+1 < nk) asm volatile("s_waitcnt vmcnt(4)" ::: "memory");
    else           asm volatile("s_waitcnt vmcnt(0)" ::: "memory");
    __builtin_amdgcn_s_barrier();
    const USHORT* At = (const USHORT*)(smem + cur*8192);
    const USHORT* Bt = (const USHORT*)(smem + 16384 + cur*8192);
    s16x8 af[4], bf[4];
    #pragma unroll
    for (int r=0;r<4;r++) af[r] = *(const s16x8*)&At[(wr*64 + r*16 + l15)*32 + l4*8];
    #pragma unroll
    for (int c=0;c<4;c++) bf[c] = *(const s16x8*)&Bt[(wc*64 + c*16 + l15)*32 + l4*8];
    #pragma unroll
    for (int r=0;r<4;r++){
      #pragma unroll
      for (int c=0;c<4;c++)
        acc[r][c] = __builtin_amdgcn_mfma_f32_16x16x32_bf16(af[r], bf[c], acc[r][c], 0,0,0);
    }
    __builtin_amdgcn_s_barrier();
    if (kt+2 < nk) GSTAGE(cur, kt+2);
  }
  #undef GSTAGE

  #pragma unroll
  for (int r=0;r<4;r++){
    const int rowb = wr*64 + r*16 + l4*4;
    #pragma unroll
    for (int c=0;c<4;c++){
      const size_t gc = n0 + wc*64 + c*16 + l15;
      #pragma unroll
      for (int q=0;q<4;q++){
        const size_t grow = m0 + rowb + q;
        float v = acc[r][c][q];
        if ((int)gc < 128){
          float sgm = v + bias[gc];
          float e = exp2f(-sgm * 1.4426950408889634f);
          outd[grow*128 + gc] = 1.0f/(1.0f + e);
        } else {
          outB[grow*128 + (gc-128)] = v + bias2[gc-128];
        }
      }
    }
  }
}

// ---------------- chunk scan (levels 1 & 2) ----------------
__global__ __launch_bounds__(256) void k_chunkscan(
    const USHORT* __restrict__ Asrc, const float* __restrict__ dsrc,
    const float* __restrict__ Bsrc,
    USHORT* __restrict__ Mdst, float* __restrict__ vdst, int nsteps)
{
  __shared__ __align__(16) USHORT Abuf[2][128*128];
  __shared__ __align__(16) USHORT MT[2][128*136];   // MT[buf][j*136+k] = M[k][j]
  __shared__ float vbuf[2][128];
  __shared__ float dbuf[2][128];

  const int tid = threadIdx.x, lane = tid&63, wave = tid>>6;
  const int wr = wave>>1, wc = wave&1, l15 = lane&15, l4 = lane>>4;
  const size_t blk = blockIdx.x;

  for (int idx=tid; idx<2176; idx+=256) ((uint4*)&MT[0][0])[idx] = make_uint4(0,0,0,0);
  __syncthreads();
  if (tid<128){ MT[0][tid*136+tid] = 0x3F80; vbuf[0][tid] = 0.f; }

  f32x4 Mreg[4][4];
  #pragma unroll
  for (int r=0;r<4;r++){
    #pragma unroll
    for (int c=0;c<4;c++){
      #pragma unroll
      for (int q=0;q<4;q++){
        int i = wr*64+r*16+l4*4+q, j = wc*64+c*16+l15;
        Mreg[r][c][q] = (i==j) ? 1.f : 0.f;
      }
    }
  }

  const int xb16   = ((tid&15)^(tid>>4))<<4;
  const int rowoff = (tid>>4)*256;

  #define CS_STAGE(buf, t) do { \
    const char* _b = (const char*)Asrc + ((size_t)(blk*nsteps + (t))<<15); \
    _Pragma("unroll") \
    for (int j=0;j<8;j++) \
      glds16(_b + j*4096 + rowoff + xb16, (char*)&Abuf[buf][0] + j*4096 + wave*1024); \
    if (dsrc && tid<128) \
      glds4((const char*)(dsrc + (size_t)(blk*nsteps + (t))*128) + tid*4, \
            (char*)&dbuf[buf][0] + (tid>>6)*256); \
  } while(0)

  CS_STAGE(0, 0);
  __syncthreads();

  int cur = 0;
  for (int t=0; t<nsteps; ++t){
    const int nxt = cur^1;
    if (t+1 < nsteps) CS_STAGE(nxt, t+1);

    f32x4 pacc[4][4];
    #pragma unroll
    for (int r=0;r<4;r++){
      #pragma unroll
      for (int c=0;c<4;c++) pacc[r][c] = f32x4{0.f,0.f,0.f,0.f};
    }
    #pragma unroll
    for (int kb=0; kb<4; ++kb){
      s16x8 af[4], bfr[4];
      #pragma unroll
      for (int r=0;r<4;r++){
        const int ra = wr*64 + r*16 + l15;
        af[r] = *(const s16x8*)&Abuf[cur][ra*128 + (((kb*4+l4)^l15)<<3)];
      }
      #pragma unroll
      for (int c=0;c<4;c++) bfr[c] = *(const s16x8*)&MT[cur][(wc*64 + c*16 + l15)*136 + kb*32 + l4*8];
      #pragma unroll
      for (int r=0;r<4;r++){
        #pragma unroll
        for (int c=0;c<4;c++)
          pacc[r][c] = __builtin_amdgcn_mfma_f32_16x16x32_bf16(af[r], bfr[c], pacc[r][c], 0,0,0);
      }
    }
    if (dsrc){
      #pragma unroll
      for (int r=0;r<4;r++){
        const int ib = wr*64 + r*16 + l4*4;
        #pragma unroll
        for (int q=0;q<4;q++){
          const float dv = dbuf[cur][ib+q];
          #pragma unroll
          for (int c=0;c<4;c++) pacc[r][c][q] += dv * Mreg[r][c][q];
        }
      }
    }
    #pragma unroll
    for (int r=0;r<4;r++){
      const int ib = wr*64 + r*16 + l4*4;
      #pragma unroll
      for (int c=0;c<4;c++){
        const int j = wc*64 + c*16 + l15;
        USHORT o0 = f2bf(pacc[r][c][0]), o1 = f2bf(pacc[r][c][1]);
        USHORT o2 = f2bf(pacc[r][c][2]), o3 = f2bf(pacc[r][c][3]);
        *(uint2*)&MT[nxt][j*136 + ib] =
            make_uint2((unsigned)o0 | ((unsigned)o1<<16), (unsigned)o2 | ((unsigned)o3<<16));
        Mreg[r][c] = pacc[r][c];
      }
    }
    if (tid<128){
      float acc = 0.f;
      const float* hv = &vbuf[cur][0];
      #pragma unroll
      for (int kb2=0; kb2<16; ++kb2){
        uint4 av = *(const uint4*)&Abuf[cur][tid*128 + ((kb2^(tid&15))<<3)];
        float4 h0 = *(const float4*)(hv + kb2*8);
        float4 h1 = *(const float4*)(hv + kb2*8 + 4);
        acc += bflo(av.x)*h0.x + bfhi(av.x)*h0.y + bflo(av.y)*h0.z + bfhi(av.y)*h0.w
             + bflo(av.z)*h1.x + bfhi(av.z)*h1.y + bflo(av.w)*h1.z + bfhi(av.w)*h1.w;
      }
      if (dsrc) acc += dbuf[cur][tid]*vbuf[cur][tid];
      acc += Bsrc[(size_t)(blk*nsteps + t)*128 + tid];
      vbuf[nxt][tid] = acc;
    }
    __syncthreads();
    cur = nxt;
  }
  {
    USHORT* gm = Mdst + blk*16384;
    #pragma unroll
    for (int it=0; it<8; ++it){
      int flat = it*256 + tid;
      int i = flat>>4, k0 = (flat&15)<<3;
      USHORT tmp[8];
      #pragma unroll
      for (int e=0;e<8;e++) tmp[e] = MT[cur][(k0+e)*136 + i];
      uint4 o;
      o.x = (unsigned)tmp[0] | ((unsigned)tmp[1]<<16);
      o.y = (unsigned)tmp[2] | ((unsigned)tmp[3]<<16);
      o.z = (unsigned)tmp[4] | ((unsigned)tmp[5]<<16);
      o.w = (unsigned)tmp[6] | ((unsigned)tmp[7]<<16);
      *(uint4*)(gm + i*128 + k0) = o;
    }
    if (tid<128) vdst[blk*128 + tid] = vbuf[cur][tid];
  }
  #undef CS_STAGE
}

// ---------------- super scan (per slab) ----------------
__global__ __launch_bounds__(128) void k_superscan(const USHORT* __restrict__ Ms,
    const float* __restrict__ vs, float* __restrict__ hss, int spb)
{
  __shared__ float hl[128];
  int b = blockIdx.x, tid = threadIdx.x;
  hl[tid] = 0.f;
  __syncthreads();
  for (int s=0;s<spb;s++){
    size_t idx = (size_t)b*spb + s;
    hss[idx*128 + tid] = hl[tid];
    const USHORT* M = Ms + idx*16384 + (size_t)tid*128;
    float acc = 0.f;
    #pragma unroll
    for (int kb=0;kb<16;kb++){
      uint4 av = *(const uint4*)(M + kb*8);
      float4 h0 = *(const float4*)&hl[kb*8];
      float4 h1 = *(const float4*)&hl[kb*8+4];
      acc += bflo(av.x)*h0.x + bfhi(av.x)*h0.y + bflo(av.y)*h0.z + bfhi(av.y)*h0.w
           + bflo(av.z)*h1.x + bfhi(av.z)*h1.y + bflo(av.w)*h1.z + bfhi(av.w)*h1.w;
    }
    acc += vs[idx*128 + tid];
    __syncthreads();
    hl[tid] = acc;
    __syncthreads();
  }
}

// ---------------- chunk starts ----------------
__global__ __launch_bounds__(128) void k_chunkstarts(const USHORT* __restrict__ Mc,
    const float* __restrict__ vc, const float* __restrict__ hss, float* __restrict__ hcs)
{
  __shared__ float hl[128];
  int s = blockIdx.x, tid = threadIdx.x;
  hl[tid] = hss[(size_t)s*128 + tid];
  __syncthreads();
  for (int g=0; g<8; ++g){
    size_t c = (size_t)s*8 + g;
    hcs[c*128 + tid] = hl[tid];
    const USHORT* M = Mc + c*16384 + (size_t)tid*128;
    float acc = 0.f;
    #pragma unroll
    for (int kb=0;kb<16;kb++){
      uint4 av = *(const uint4*)(M + kb*8);
      float4 h0 = *(const float4*)&hl[kb*8];
      float4 h1 = *(const float4*)&hl[kb*8+4];
      acc += bflo(av.x)*h0.x + bfhi(av.x)*h0.y + bflo(av.y)*h0.z + bfhi(av.y)*h0.w
           + bflo(av.z)*h1.x + bfhi(av.z)*h1.y + bflo(av.w)*h1.z + bfhi(av.w)*h1.w;
    }
    acc += vc[c*128 + tid];
    __syncthreads();
    hl[tid] = acc;
    __syncthreads();
  }
}

// ---------------- phase 3: serial replay of chunk from its start state ----------------
__global__ __launch_bounds__(256) void k_phase3(
    const USHORT* __restrict__ Asrc, const float* __restrict__ dsrc,
    const float* __restrict__ Bsrc, const float* __restrict__ hcs,
    float* __restrict__ hs, int nsteps)
{
  __shared__ __align__(16) USHORT Abuf[2][128*128];
  __shared__ float hb[2][128];
  __shared__ float db[2][128];
  const int tid = threadIdx.x, wave = tid>>6;
  const size_t blk = blockIdx.x;
  const int xb16   = ((tid&15)^(tid>>4))<<4;
  const int rowoff = (tid>>4)*256;

  #define P3_STAGE(buf, t) do { \
    const char* _b = (const char*)Asrc + ((size_t)(blk*nsteps + (t))<<15); \
    _Pragma("unroll") \
    for (int j=0;j<8;j++) \
      glds16(_b + j*4096 + rowoff + xb16, (char*)&Abuf[buf][0] + j*4096 + wave*1024); \
    if (tid<128) \
      glds4((const char*)(dsrc + (size_t)(blk*nsteps + (t))*128) + tid*4, \
            (char*)&db[buf][0] + (tid>>6)*256); \
  } while(0)

  P3_STAGE(0, 0);
  if (tid<128) hb[0][tid] = hcs[blk*128 + tid];
  __syncthreads();

  int cur = 0;
  for (int t=0; t<nsteps; ++t){
    const int nxt = cur^1;
    if (t+1 < nsteps) P3_STAGE(nxt, t+1);
    if (tid<128){
      float acc = 0.f;
      const float* hv = &hb[cur][0];
      #pragma unroll
      for (int kb=0;kb<16;kb++){
        uint4 av = *(const uint4*)&Abuf[cur][tid*128 + ((kb^(tid&15))<<3)];
        float4 h0 = *(const float4*)(hv + kb*8);
        float4 h1 = *(const float4*)(hv + kb*8+4);
        acc += bflo(av.x)*h0.x + bfhi(av.x)*h0.y + bflo(av.y)*h0.z + bfhi(av.y)*h0.w
             + bflo(av.z)*h1.x + bfhi(av.z)*h1.y + bflo(av.w)*h1.z + bfhi(av.w)*h1.w;
      }
      acc += db[cur][tid]*hb[cur][tid];
      acc += Bsrc[(size_t)(blk*nsteps + t)*128 + tid];
      hs[(size_t)(blk*nsteps + t)*128 + tid] = acc;
      hb[nxt][tid] = acc;
    }
    __syncthreads();
    cur = nxt;
  }
  #undef P3_STAGE
}

// ---------------- output: y = hs @ C + D_skip * u ----------------
__global__ __launch_bounds__(256) void k_out(const float* __restrict__ hs,
    const float* __restrict__ Cm, const float* __restrict__ Dsk,
    const float* __restrict__ u, float* __restrict__ y)
{
  __shared__ float hsl[8][128];
  const int tid = threadIdx.x;
  const size_t tk0 = (size_t)blockIdx.x*8;
  for (int i=tid; i<1024; i+=256) hsl[i>>7][i&127] = hs[tk0*128 + i];
  __syncthreads();
  #pragma unroll
  for (int dc=0; dc<4; ++dc){
    const int d = dc*256 + tid;
    float a0=0,a1=0,a2=0,a3=0,a4=0,a5=0,a6=0,a7=0;
    for (int n=0;n<128;++n){
      float cv = Cm[(size_t)n*1024 + d];
      a0 += hsl[0][n]*cv; a1 += hsl[1][n]*cv; a2 += hsl[2][n]*cv; a3 += hsl[3][n]*cv;
      a4 += hsl[4][n]*cv; a5 += hsl[5][n]*cv; a6 += hsl[6][n]*cv; a7 += hsl[7][n]*cv;
    }
    float dd = Dsk[d];
    float av[8] = {a0,a1,a2,a3,a4,a5,a6,a7};
    #pragma unroll
    for (int tkk=0;tkk<8;tkk++){
      size_t idx = (tk0+tkk)*1024 + d;
      y[idx] = av[tkk] + dd*u[idx];
    }
  }
}

__global__ void k_report(float* out, float val){
  if (threadIdx.x==0 && blockIdx.x==0) out[0] = val;
}

extern "C" void kernel_launch(void* const* d_in, const int* in_sizes, int n_in,
                              void* d_out, int out_size, void* d_ws, size_t ws_size,
                              hipStream_t stream)
{
  const float* u   = (const float*)d_in[0];
  const float* Wd  = (const float*)d_in[1];
  const float* bd  = (const float*)d_in[2];
  const float* WA  = (const float*)d_in[3];
  const float* bA  = (const float*)d_in[4];
  const float* WB  = (const float*)d_in[5];
  const float* bB  = (const float*)d_in[6];
  const float* Cm  = (const float*)d_in[7];
  const float* Dsk = (const float*)d_in[8];
  float* y = (float*)d_out;
  (void)in_sizes; (void)n_in; (void)out_size;

  int NSLAB;
  if      (ws_size >= 208000000ull) NSLAB = 2;
  else if (ws_size >= 136000000ull) NSLAB = 4;
  else { k_report<<<1, 64, 0, stream>>>(y, (float)(ws_size >> 20)); return; }

  const int L = 16;
  const int rowsSlab   = 8192/NSLAB;
  const int cps        = rowsSlab/L;
  const int supersSlab = cps/8;
  const int batchSlab  = 4/NSLAB;

  char* w = (char*)d_ws;
  size_t off = 0;
  auto take = [&](size_t bytes)->char*{ char* p = w + off; off += (bytes+255)&~(size_t)255; return p; };
  USHORT* u_bf  = (USHORT*)take(8192ull*1024*2);
  USHORT* WAT   = (USHORT*)take(16384ull*1024*2);
  USHORT* W2    = (USHORT*)take(256ull*1024*2);
  float*  d_arr = (float*)take(8192ull*128*4);
  float*  Btv   = (float*)take(8192ull*128*4);
  USHORT* Amat  = (USHORT*)take((size_t)rowsSlab*16384*2);
  USHORT* Mc    = (USHORT*)take((size_t)cps*16384*2);
  float*  vc    = (float*)take((size_t)cps*128*4);
  USHORT* Ms    = (USHORT*)take((size_t)supersSlab*16384*2);
  float*  vs    = (float*)take((size_t)supersSlab*128*4);
  float*  hss   = (float*)take((size_t)supersSlab*128*4);
  float*  hcs   = (float*)take((size_t)cps*128*4);
  float*  hs    = (float*)take(8192ull*128*4);

  k_convert<<<2048, 256, 0, stream>>>(u, u_bf, 8192*1024/4);
  k_transpose<<<dim3(16,256), 256, 0, stream>>>(WA, WAT, 1024, 16384);
  k_transpose<<<dim3(16,2), 256, 0, stream>>>(Wd, W2, 1024, 128);
  k_transpose<<<dim3(16,2), 256, 0, stream>>>(WB, W2 + 128*1024, 1024, 128);
  k_gemmdb<<<dim3(64,2), 256, 0, stream>>>(u_bf, W2, bd, bB, d_arr, Btv, 1024);

  for (int s=0; s<NSLAB; ++s){
    const size_t r0 = (size_t)s*rowsSlab;
    k_gemm256<<<dim3(rowsSlab/256,64), 512, 0, stream>>>(u_bf + r0*1024, WAT, bA, Amat, 1024);
    k_chunkscan<<<cps, 256, 0, stream>>>(Amat, d_arr + r0*128, Btv + r0*128, Mc, vc, L);
    k_chunkscan<<<supersSlab, 256, 0, stream>>>(Mc, nullptr, vc, Ms, vs, 8);
    k_superscan<<<batchSlab, 128, 0, stream>>>(Ms, vs, hss, supersSlab/batchSlab);
    k_chunkstarts<<<supersSlab, 128, 0, stream>>>(Mc, vc, hss, hcs);
    k_phase3<<<cps, 256, 0, stream>>>(Amat, d_arr + r0*128, Btv + r0*128,
                                      hcs, hs + r0*128, L);
  }
  k_out<<<1024, 256, 0, stream>>>(hs, Cm, Dsk, u, y);
}